// Round 1
// baseline (230.457 us; speedup 1.0000x reference)
//
#include <hip/hip_runtime.h>

// LocBlock2dNT: x (64,64,64,64) f32, w (256,64,16,16,16) f32
// out (64,256,16,16) f32 = relu( einsum('ncpqf,ocpqf->nopq', patches, w) / 32 )
// One block per (p,q): GEMM M=64(n) x N=256(o) x K=1024(c*16+k), bf16 MFMA.

typedef short bf16x8 __attribute__((ext_vector_type(8)));
typedef float f32x4  __attribute__((ext_vector_type(4)));

__device__ __forceinline__ short f2bf(float f) {
    union { float f; unsigned u; } v; v.f = f;
    return (short)((v.u + 0x7FFFu + ((v.u >> 16) & 1u)) >> 16);   // RNE
}

__device__ __forceinline__ bf16x8 pack8(f32x4 a, f32x4 b) {
    bf16x8 r;
    r[0] = f2bf(a[0]); r[1] = f2bf(a[1]); r[2] = f2bf(a[2]); r[3] = f2bf(a[3]);
    r[4] = f2bf(b[0]); r[5] = f2bf(b[1]); r[6] = f2bf(b[2]); r[7] = f2bf(b[3]);
    return r;
}

__global__ __launch_bounds__(512)
void locblock_mfma(const float* __restrict__ x, const float* __restrict__ w,
                   float* __restrict__ out) {
    // XCD swizzle: 32 consecutive logical (p,q) per XCD -> L2 merges the
    // 64B half-lines of w / x / out shared between adjacent q.
    const int hw  = blockIdx.x;
    const int bid = (hw & 7) * 32 + (hw >> 3);       // bijective, 256 % 8 == 0
    const int p = bid >> 4, q = bid & 15;

    const int lane = threadIdx.x & 63;
    const int wave = threadIdx.x >> 6;               // 0..7, owns o in [wave*32, wave*32+32)
    const int l15  = lane & 15;
    const int kq   = lane >> 4;                      // 0..3: k = t*32 + kq*8 + j

    // K decomposition: K = c*16 + (fr*4 + fc).  Per step t (BK=32):
    //   c  = 2t + (kq>>1),  within-c k16 = (kq&1)*8  -> rows fr0=2*(kq&1), fr0+1
    const int coff = kq >> 1;
    const int fr   = (kq & 1) * 2;

    // x strides (floats): n:262144, c:4096, row:64, col:1
    const float* xb[4];
#pragma unroll
    for (int mf = 0; mf < 4; ++mf) {
        const int n = mf * 16 + l15;                 // A row = lane&15
        xb[mf] = x + ((size_t)n * 262144u + (size_t)coff * 4096u
                      + (size_t)(4 * p + fr) * 64u + (size_t)(4 * q));
    }
    // w strides (floats): o:262144, c:4096, p:256, q:16, k:1
    const float* wb[2];
#pragma unroll
    for (int nf = 0; nf < 2; ++nf) {
        const int o = wave * 32 + nf * 16 + l15;     // B col = lane&15
        wb[nf] = w + ((size_t)o * 262144u + (size_t)coff * 4096u
                      + (size_t)p * 256u + (size_t)q * 16u
                      + (size_t)((kq & 1) * 8));
    }

    f32x4 acc[4][2];
#pragma unroll
    for (int mf = 0; mf < 4; ++mf)
#pragma unroll
        for (int nf = 0; nf < 2; ++nf)
            acc[mf][nf] = (f32x4){0.f, 0.f, 0.f, 0.f};

#pragma unroll 2
    for (int t = 0; t < 32; ++t) {
        const size_t off = (size_t)t * 8192u;        // advance 2 c's per step
        bf16x8 av[4], bv[2];
#pragma unroll
        for (int mf = 0; mf < 4; ++mf) {
            f32x4 lo = *(const f32x4*)(xb[mf] + off);        // row fr,   fc 0..3
            f32x4 hi = *(const f32x4*)(xb[mf] + off + 64);   // row fr+1, fc 0..3
            av[mf] = pack8(lo, hi);
        }
#pragma unroll
        for (int nf = 0; nf < 2; ++nf) {
            f32x4 lo = *(const f32x4*)(wb[nf] + off);        // k 8 contiguous
            f32x4 hi = *(const f32x4*)(wb[nf] + off + 4);
            bv[nf] = pack8(lo, hi);
        }
#pragma unroll
        for (int mf = 0; mf < 4; ++mf)
#pragma unroll
            for (int nf = 0; nf < 2; ++nf)
                acc[mf][nf] = __builtin_amdgcn_mfma_f32_16x16x32_bf16(
                    av[mf], bv[nf], acc[mf][nf], 0, 0, 0);
    }

    // C/D layout (m89): col = lane&15 (=o), row = (lane>>4)*4 + j (=n)
    const float scale = 0.03125f;                    // 1/sqrt(16*64)
    const int pq = p * 16 + q;
    const int rbase = kq * 4;
#pragma unroll
    for (int mf = 0; mf < 4; ++mf)
#pragma unroll
        for (int nf = 0; nf < 2; ++nf) {
            const int o = wave * 32 + nf * 16 + l15;
#pragma unroll
            for (int j = 0; j < 4; ++j) {
                const int n = mf * 16 + rbase + j;
                const float v = acc[mf][nf][j] * scale;
                out[(size_t)n * 65536u + (size_t)o * 256u + (size_t)pq] =
                    fmaxf(v, 0.0f);
            }
        }
}

extern "C" void kernel_launch(void* const* d_in, const int* in_sizes, int n_in,
                              void* d_out, int out_size, void* d_ws, size_t ws_size,
                              hipStream_t stream) {
    const float* x = (const float*)d_in[0];
    const float* w = (const float*)d_in[1];
    float* out = (float*)d_out;
    locblock_mfma<<<dim3(256), dim3(512), 0, stream>>>(x, w, out);
}

// Round 2
// 110.222 us; speedup vs baseline: 2.0908x; 2.0908x over previous
//
#include <hip/hip_runtime.h>

// LocBlock2dNT: x (64,64,64,64) f32, w (256,64,16,16,16) f32
// out (64,256,16,16) f32 = relu( einsum('ncpqf,ocpqf->nopq', patches, w) / 32 )
// One block per (p,q): GEMM M=64(n) x N=256(o) x K=1024, bf16 MFMA.
// Pipeline: global_load_lds double-buffer, counted vmcnt, raw s_barrier.

typedef short bf16x8 __attribute__((ext_vector_type(8)));
typedef float f32x4  __attribute__((ext_vector_type(4)));

__device__ __forceinline__ short f2bf(float f) {
    union { float f; unsigned u; } v; v.f = f;
    return (short)((v.u + 0x7FFFu + ((v.u >> 16) & 1u)) >> 16);   // RNE
}

__device__ __forceinline__ bf16x8 pack8(f32x4 a, f32x4 b) {
    bf16x8 r;
    r[0] = f2bf(a[0]); r[1] = f2bf(a[1]); r[2] = f2bf(a[2]); r[3] = f2bf(a[3]);
    r[4] = f2bf(b[0]); r[5] = f2bf(b[1]); r[6] = f2bf(b[2]); r[7] = f2bf(b[3]);
    return r;
}

__device__ __forceinline__ void gload16(const void* g, void* l) {
    __builtin_amdgcn_global_load_lds(
        (const __attribute__((address_space(1))) void*)g,
        (__attribute__((address_space(3))) void*)l, 16, 0, 0);
}

__global__ __launch_bounds__(512)
void locblock_mfma(const float* __restrict__ x, const float* __restrict__ w,
                   float* __restrict__ out) {
    // [buf][ A tile 8 KB | B tile 32 KB ]  = 80 KB total
    __shared__ __align__(16) char smem[2][40960];

    // XCD swizzle: 32 consecutive logical (p,q) per XCD (L2 line sharing for
    // w/x fetch halves and out writes).
    const int hw  = blockIdx.x;
    const int bid = (hw & 7) * 32 + (hw >> 3);       // bijective, 256 % 8 == 0
    const int p = bid >> 4, q = bid & 15;

    const int tid  = (int)threadIdx.x;
    const int lane = tid & 63;
    const int wv   = tid >> 6;                       // 0..7
    const int l15  = lane & 15;
    const int kq   = lane >> 4;                      // 0..3

    // ---- staging global sources (t=0); advance 8192 floats per step ----
    // A tile: 512 chunks of 16B, chunk = tid. Logical chunk (n, cfr) stored
    // at (n, cfr); data comes from cfr_src = cfr ^ (n&7)  (swizzle on SOURCE,
    // LDS dest stays linear for global_load_lds).
    // cfr decomposition: cfr = c_off*4 + fr  (c_off in 0..1, fr in 0..3)
    const int an   = tid >> 3;
    const int acfs = (tid & 7) ^ (an & 7);
    const float* asrc = x + (size_t)an * 262144u + (size_t)(acfs >> 2) * 4096u
                          + (size_t)(4 * p + (acfs & 3)) * 64u + (size_t)(4 * q);
    // B tile: 2048 chunks of 16B, 4 issues/thread, chunk = wv*256 + j*64 + lane.
    // Logical (o, cfr) with cfr = c_off*4 + k0 ; source cfr_src = cfr ^ (o&7).
    const float* bsrc[4];
#pragma unroll
    for (int j = 0; j < 4; ++j) {
        const int chunk = wv * 256 + j * 64 + lane;
        const int o   = chunk >> 3;
        const int cfs = (chunk & 7) ^ (o & 7);
        bsrc[j] = w + (size_t)o * 262144u + (size_t)(cfs >> 2) * 4096u
                    + (size_t)p * 256u + (size_t)q * 16u + (size_t)((cfs & 3) * 4);
    }

    // ---- LDS fragment-read offsets (in floats, within a buffer) ----
    // Wanted logical cfr pair for this lane: 2*kq and 2*kq+1 (c_off=kq>>1,
    // fr/k0 base=(kq&1)*2). Stored at cfr ^ (row&7).
    int aofs[4][2], bofs[2][2];
#pragma unroll
    for (int mf = 0; mf < 4; ++mf) {
        const int n = mf * 16 + l15;
        aofs[mf][0] = (n * 8 + ((2 * kq)     ^ (n & 7))) * 4;
        aofs[mf][1] = (n * 8 + ((2 * kq + 1) ^ (n & 7))) * 4;
    }
#pragma unroll
    for (int nf = 0; nf < 2; ++nf) {
        const int o = wv * 32 + nf * 16 + l15;
        bofs[nf][0] = (o * 8 + ((2 * kq)     ^ (o & 7))) * 4;
        bofs[nf][1] = (o * 8 + ((2 * kq + 1) ^ (o & 7))) * 4;
    }

    f32x4 acc[4][2];
#pragma unroll
    for (int mf = 0; mf < 4; ++mf)
#pragma unroll
        for (int nf = 0; nf < 2; ++nf)
            acc[mf][nf] = (f32x4){0.f, 0.f, 0.f, 0.f};

    auto stage = [&](int t, int buf) {
        char* base = smem[buf];
        const size_t toff = (size_t)t * 8192u;           // 2 c's per step
        gload16(asrc + toff, base + wv * 1024);          // 1 KB per wave
#pragma unroll
        for (int j = 0; j < 4; ++j)
            gload16(bsrc[j] + toff, base + 8192 + wv * 4096 + j * 1024);
    };

    auto compute = [&](int buf) {
        const float* Ab = (const float*)(smem[buf]);
        const float* Bb = (const float*)(smem[buf] + 8192);
        bf16x8 av[4], bv[2];
#pragma unroll
        for (int mf = 0; mf < 4; ++mf)
            av[mf] = pack8(*(const f32x4*)(Ab + aofs[mf][0]),
                           *(const f32x4*)(Ab + aofs[mf][1]));
#pragma unroll
        for (int nf = 0; nf < 2; ++nf)
            bv[nf] = pack8(*(const f32x4*)(Bb + bofs[nf][0]),
                           *(const f32x4*)(Bb + bofs[nf][1]));
#pragma unroll
        for (int mf = 0; mf < 4; ++mf)
#pragma unroll
            for (int nf = 0; nf < 2; ++nf)
                acc[mf][nf] = __builtin_amdgcn_mfma_f32_16x16x32_bf16(
                    av[mf], bv[nf], acc[mf][nf], 0, 0, 0);
    };

    // ---- pipelined main loop: 32 K-steps, 2-deep prefetch ----
    stage(0, 0);
    stage(1, 1);
#pragma unroll 1
    for (int t = 0; t < 30; ++t) {
        const int cur = t & 1;
        // wait for oldest stage (5 loads/thread); keep next 5 in flight
        asm volatile("s_waitcnt vmcnt(5)" ::: "memory");
        __builtin_amdgcn_s_barrier();
        compute(cur);
        asm volatile("s_waitcnt lgkmcnt(0)" ::: "memory");  // reads retired
        __builtin_amdgcn_s_barrier();
        stage(t + 2, cur);
    }
    // t = 30
    asm volatile("s_waitcnt vmcnt(5)" ::: "memory");
    __builtin_amdgcn_s_barrier();
    compute(0);
    // t = 31 (drain)
    asm volatile("s_waitcnt vmcnt(0)" ::: "memory");
    __builtin_amdgcn_s_barrier();
    compute(1);

    // ---- epilogue: C/D layout col=lane&15 (=o frag), row=kq*4+j (=n frag) ----
    const float scale = 0.03125f;                    // 1/sqrt(16*64)
    const int pq = p * 16 + q;
    const int rbase = kq * 4;
#pragma unroll
    for (int mf = 0; mf < 4; ++mf)
#pragma unroll
        for (int nf = 0; nf < 2; ++nf) {
            const int o = wv * 32 + nf * 16 + l15;
#pragma unroll
            for (int j = 0; j < 4; ++j) {
                const int n = mf * 16 + rbase + j;
                const float v = acc[mf][nf][j] * scale;
                out[(size_t)n * 65536u + (size_t)o * 256u + (size_t)pq] =
                    fmaxf(v, 0.0f);
            }
        }
}

extern "C" void kernel_launch(void* const* d_in, const int* in_sizes, int n_in,
                              void* d_out, int out_size, void* d_ws, size_t ws_size,
                              hipStream_t stream) {
    const float* x = (const float*)d_in[0];
    const float* w = (const float*)d_in[1];
    float* out = (float*)d_out;
    locblock_mfma<<<dim3(256), dim3(512), 0, stream>>>(x, w, out);
}